// Round 6
// baseline (782.687 us; speedup 1.0000x reference)
//
#include <hip/hip_runtime.h>
#include <cstdint>
#include <math.h>

// Problem constants
#define B_   4
#define T_   2048
#define D_   1024
#define H_   8
#define DK_  128
#define P_   4095   // 2T-1
#define PS_  4096   // padded P rows per head (row 4095 = finite junk, never a real score)

typedef unsigned short ushort_t;
typedef __attribute__((ext_vector_type(8))) short short8;
typedef __attribute__((ext_vector_type(4))) float floatx4;

__device__ inline float bf2f(ushort_t s) {
    return __uint_as_float(((unsigned int)s) << 16);
}
__device__ inline ushort_t f2bf(float f) {
    unsigned int u = __float_as_uint(f);
    u += 0x7fffu + ((u >> 16) & 1u);   // round-to-nearest-even
    return (ushort_t)(u >> 16);
}

__device__ inline floatx4 mfma16(short8 a, short8 b, floatx4 c) {
    return __builtin_amdgcn_mfma_f32_16x16x32_bf16(a, b, c, 0, 0, 0);
}

// async global->LDS, 16B per lane; LDS dest = wave-uniform base + lane*16
__device__ inline void gload_lds16(const ushort_t* g, ushort_t* l) {
    __builtin_amdgcn_global_load_lds(
        (const __attribute__((address_space(1))) unsigned int*)g,
        (__attribute__((address_space(3))) unsigned int*)l, 16, 0, 0);
}

// dtype detector: flag 0 = bf16 inputs, 1 = fp32 inputs.
__global__ void detect_kernel(const ushort_t* x, int* flag) {
    if (blockIdx.x == 0 && threadIdx.x == 0) {
        int m = 0;
        for (int i = 0; i < 64; ++i) {
            float v = bf2f(x[2 * i]);
            float a = fabsf(v);
            if (!(a == 0.0f || (a > 1e-20f && a < 1e10f))) m = 1;
        }
        flag[0] = m;
    }
}

// ---------------------------------------------------------------------------
// Conversion: all external tensors -> contiguous bf16 arena.
// ---------------------------------------------------------------------------
#define CV_TOT 17826816
template <int MODE>
__global__ __launch_bounds__(256) void convert_kernel(
    const int* __restrict__ flag,
    const void* __restrict__ x, const void* __restrict__ pe,
    const void* __restrict__ wq, const void* __restrict__ wk,
    const void* __restrict__ wv, const void* __restrict__ wo,
    const void* __restrict__ wp, const void* __restrict__ ub,
    const void* __restrict__ vb, ushort_t* __restrict__ dst)
{
    if (flag[0] != MODE) return;
    const size_t i = ((size_t)blockIdx.x * 256 + threadIdx.x) * 4;
    if (i >= CV_TOT) return;
    const void* s; size_t off;
    if (i < 8388608)       { s = x;  off = i; }
    else if (i < 12581888) { s = pe; off = i - 8388608; }
    else if (i < 13630464) { s = wq; off = i - 12581888; }
    else if (i < 14679040) { s = wk; off = i - 13630464; }
    else if (i < 15727616) { s = wv; off = i - 14679040; }
    else if (i < 16776192) { s = wo; off = i - 15727616; }
    else if (i < 17824768) { s = wp; off = i - 16776192; }
    else if (i < 17825792) { s = ub; off = i - 17824768; }
    else                   { s = vb; off = i - 17825792; }
    const size_t d = i + (i >= 12581888 ? 1024 : 0);
    if (MODE == 0) {
        *(uint2*)(dst + d) = *(const uint2*)((const ushort_t*)s + off);
    } else {
        float4 f = *(const float4*)((const float*)s + off);
        uint2 o;
        o.x = (unsigned)f2bf(f.x) | ((unsigned)f2bf(f.y) << 16);
        o.y = (unsigned)f2bf(f.z) | ((unsigned)f2bf(f.w) << 16);
        *(uint2*)(dst + d) = o;
    }
}

// ---------------------------------------------------------------------------
// MFMA GEMM, double-buffered: C[m,n] = sum_k A[m,k]*W[n,k], K=1024.
// 128x128 tile, BK=64, 4 waves 2x2 (each 64x64). LDS in fragment order;
// next K-slab issued via global_load_lds BEFORE computing current slab, so
// the vmcnt(0) drain at the barrier completes against already-landed loads.
// smode: 5 -> fused QKV scatter (W rows 0..3071 = Wq|Wk|Wv; C = q_ws base,
//        k at +8388608, v-transposed at +16777216); 1 -> P [H,PS,DK];
//        3 -> row-major bf16 out (iff flag==0); 4 -> row-major fp32 (flag==1)
// ---------------------------------------------------------------------------
__global__ __launch_bounds__(256, 2) void gemm_mfma(
    const int* __restrict__ flag,
    const ushort_t* __restrict__ A, const ushort_t* __restrict__ W,
    void* __restrict__ C, int smode)
{
    if (smode == 3 && flag[0] != 0) return;
    if (smode == 4 && flag[0] != 1) return;

    __shared__ ushort_t Al[2][8192];   // 2 x 16 units x 512 ushorts (32KB)
    __shared__ ushort_t Wl[2][8192];

    const int tid  = threadIdx.x;
    const int w    = tid >> 6, lane = tid & 63;
    const int r15  = lane & 15, quad = lane >> 4;
    const int wm   = w >> 1, wn = w & 1;
    const int m0   = blockIdx.y * 128, n0 = blockIdx.x * 128;

    floatx4 acc[4][4];
    const floatx4 z4 = {0.f, 0.f, 0.f, 0.f};
#pragma unroll
    for (int mt = 0; mt < 4; ++mt)
#pragma unroll
        for (int nt = 0; nt < 4; ++nt) acc[mt][nt] = z4;

    auto stage = [&](int bfi, int k0) {
#pragma unroll
        for (int ss = 0; ss < 4; ++ss) {
            const int s  = w * 4 + ss;
            const int mg = s >> 1, ks = s & 1;
            const int row = mg * 16 + r15;
            const int col = k0 + ks * 32 + quad * 8;
            gload_lds16(A + (size_t)(m0 + row) * 1024 + col, &Al[bfi][s * 512]);
            gload_lds16(W + (size_t)(n0 + row) * 1024 + col, &Wl[bfi][s * 512]);
        }
    };

    stage(0, 0);
    __syncthreads();

    for (int k0 = 0; k0 < 1024; k0 += 64) {
        const int cur = (k0 >> 6) & 1;
        if (k0 + 64 < 1024) stage(cur ^ 1, k0 + 64);   // early issue

        short8 af[2][4], bf[2][4];
#pragma unroll
        for (int ks = 0; ks < 2; ++ks) {
#pragma unroll
            for (int mt = 0; mt < 4; ++mt)
                af[ks][mt] = *(const short8*)&Al[cur][(((wm * 4 + mt) * 2 + ks) * 64 + lane) * 8];
#pragma unroll
            for (int nt = 0; nt < 4; ++nt)
                bf[ks][nt] = *(const short8*)&Wl[cur][(((wn * 4 + nt) * 2 + ks) * 64 + lane) * 8];
        }
#pragma unroll
        for (int ks = 0; ks < 2; ++ks)
#pragma unroll
            for (int mt = 0; mt < 4; ++mt)
#pragma unroll
                for (int nt = 0; nt < 4; ++nt)
                    acc[mt][nt] = mfma16(af[ks][mt], bf[ks][nt], acc[mt][nt]);
        __syncthreads();
    }

    // epilogue (C-layout: row = quad*4+i, col = r15)
#pragma unroll
    for (int mt = 0; mt < 4; ++mt)
#pragma unroll
        for (int nt = 0; nt < 4; ++nt)
#pragma unroll
            for (int i = 0; i < 4; ++i) {
                const int m = m0 + wm * 64 + mt * 16 + quad * 4 + i;
                const int n = n0 + wn * 64 + nt * 16 + r15;
                const float v = acc[mt][nt][i];
                if (smode == 5) {
                    const int nh = n >> 10, nl = n & 1023;
                    const int hh = nl >> 7, dk = nl & 127;
                    const int bb = m >> 11, tt = m & 2047;
                    if (nh == 0)
                        ((ushort_t*)C)[(((size_t)(bb * 8 + hh)) * 2048 + tt) * 128 + dk] = f2bf(v);
                    else if (nh == 1)
                        ((ushort_t*)C)[8388608 + (((size_t)(bb * 8 + hh)) * 2048 + tt) * 128 + dk] = f2bf(v);
                    else
                        ((ushort_t*)C)[16777216 + ((size_t)(bb * 8 + hh) * 128 + dk) * 2048 + tt] = f2bf(v);
                } else if (smode == 1) {
                    const int hh = n >> 7, dk = n & 127;
                    ((ushort_t*)C)[((size_t)hh * PS_ + m) * 128 + dk] = f2bf(v);
                } else if (smode == 3) {
                    ((ushort_t*)C)[(size_t)m * 1024 + n] = f2bf(v);
                } else {
                    ((float*)C)[(size_t)m * 1024 + n] = v;
                }
            }
}

// ---------------------------------------------------------------------------
// MFMA flash attention v3, rel-shift folded:
//   score[q,k] = ((q+u)·K[k] + (q+v)·P[k-q+T-1]) / sqrt(DK)
// Block = 4 waves x 32 q-rows = 128 q-rows; K-chunk 64; grid (16, 32).
// Each wave owns 2 sub-blocks (mt=0,1) of 16 q-rows -> every K/V fragment
// read feeds 2 MFMAs; band reads feed up to 2 (windows of mt overlap).
// Pipeline: K/V double-buffered; P band in a 16-group rolling ring (window
// = 12 groups = logical 4*ib..4*ib+11; chunk i stages groups 4i+12..4i+15
// into ring slots disjoint from the live window). All next-chunk loads are
// issued BEFORE computing the current chunk.
// LDS: K 2x16KB + V 2x16KB + P 64KB + pr 16KB = 144KB -> 1 block/CU.
// ---------------------------------------------------------------------------
__global__ __launch_bounds__(256, 1) void attn_mfma(
    const ushort_t* __restrict__ qg,
    const ushort_t* __restrict__ kgl,
    const ushort_t* __restrict__ vt,   // [B,H,DK,T]
    const ushort_t* __restrict__ pg,   // [H,PS_,DK]
    const ushort_t* __restrict__ ubb,  // bf16 [H,DK]
    const ushort_t* __restrict__ vbb,
    ushort_t* __restrict__ ao)         // [B,T,D]
{
    __shared__ ushort_t K_lds[2][8192];       // 16 units (gk*4+ks) x 512
    __shared__ ushort_t V_lds[2][8192];       // 16 units (og*2+ks2) x 512
    __shared__ ushort_t P_lds[16][2048];      // ring: slot = logical_group & 15
    __shared__ __align__(16) ushort_t pr_lds[4][2][1024];

    const int tid  = threadIdx.x;
    const int w    = tid >> 6;
    const int lane = tid & 63;
    const int r15  = lane & 15;
    const int quad = lane >> 4;
    const int bh   = blockIdx.y;
    const int h    = bh & (H_ - 1);
    const int b    = bh >> 3;
    const int q0b  = blockIdx.x * 128;
    const int pbb0 = 1920 - q0b;              // >= 0 (q0b <= 1920)

    // ---- Q fragments (A-layout) with u/v biases folded; mt = sub-block ----
    short8 quA[2][4], qvA[2][4];
#pragma unroll
    for (int mt = 0; mt < 2; ++mt) {
        const ushort_t* qrow = qg + ((size_t)bh * T_ + q0b + w * 32 + mt * 16 + r15) * DK_;
#pragma unroll
        for (int ks = 0; ks < 4; ++ks) {
            const int dk0 = ks * 32 + quad * 8;
            uint4 q4 = *(const uint4*)(qrow + dk0);
            uint4 u4 = *(const uint4*)(ubb + (size_t)h * DK_ + dk0);
            uint4 v4 = *(const uint4*)(vbb + (size_t)h * DK_ + dk0);
            const ushort_t* qs = (const ushort_t*)&q4;
            const ushort_t* us = (const ushort_t*)&u4;
            const ushort_t* vs = (const ushort_t*)&v4;
#pragma unroll
            for (int j = 0; j < 8; ++j) {
                const float qf = bf2f(qs[j]);
                quA[mt][ks][j] = (short)f2bf(qf + bf2f(us[j]));
                qvA[mt][ks][j] = (short)f2bf(qf + bf2f(vs[j]));
            }
        }
    }

    // rel-shift gather lane sources (same per mt: relative to 16-row band)
    int src[4], hi[4];
#pragma unroll
    for (int i = 0; i < 4; ++i) {
        const int c = r15 + 15 - quad * 4 - i;   // in [0,30]
        src[i] = quad * 16 + (c & 15);
        hi[i]  = c >> 4;
    }

    floatx4 o[2][8];
    const floatx4 z4 = {0.f, 0.f, 0.f, 0.f};
#pragma unroll
    for (int mt = 0; mt < 2; ++mt)
#pragma unroll
        for (int g = 0; g < 8; ++g) o[mt][g] = z4;
    float mrun[2][4], lrun[2][4];
#pragma unroll
    for (int mt = 0; mt < 2; ++mt)
#pragma unroll
        for (int i = 0; i < 4; ++i) { mrun[mt][i] = -1e30f; lrun[mt][i] = 0.f; }

    const float scale = 0.08838834764831845f;  // 1/sqrt(128)

    auto stageKV = [&](int bfi, int kc) {
#pragma unroll
        for (int ss = 0; ss < 4; ++ss) {
            const int ck = w * 4 + ss;           // (gk=w, ks=ss)
            gload_lds16(kgl + ((size_t)bh * T_ + kc + w * 16 + r15) * DK_ + ss * 32 + quad * 8,
                        &K_lds[bfi][ck * 512]);
            const int og = ck >> 1, ks2 = ck & 1;
            gload_lds16(vt + ((size_t)(bh * DK_ + og * 16 + r15)) * T_ + kc + ks2 * 32 + quad * 8,
                        &V_lds[bfi][ck * 512]);
        }
    };
    auto stageP = [&](int lg) {
        const int sl = lg & 15;
        const int grow = pbb0 + lg * 16 + r15;   // <= 4095 by construction
#pragma unroll
        for (int ks = 0; ks < 4; ++ks)
            gload_lds16(pg + ((size_t)h * PS_ + grow) * DK_ + ks * 32 + quad * 8,
                        &P_lds[sl][ks * 512]);
    };

    // ---- prologue: chunk 0 K/V + P groups 0..11 ----
    stageKV(0, 0);
    stageP(w * 3);
    stageP(w * 3 + 1);
    stageP(w * 3 + 2);
    __syncthreads();

    for (int ib = 0; ib < 32; ++ib) {
        const int kc0 = ib * 64, cur = ib & 1;
        if (ib < 31) {                            // early issue for chunk ib+1
            stageKV(cur ^ 1, kc0 + 64);
            stageP(4 * ib + 12 + w);
        }

        // ---- AC = Qu x K^T (each K-frag feeds both mt) ----
        floatx4 ac[2][4];
#pragma unroll
        for (int g = 0; g < 4; ++g) { ac[0][g] = z4; ac[1][g] = z4; }
#pragma unroll
        for (int g = 0; g < 4; ++g)
#pragma unroll
            for (int ks = 0; ks < 4; ++ks) {
                const short8 kf = *(const short8*)&K_lds[cur][((g * 4 + ks) * 64 + lane) * 8];
                ac[0][g] = mfma16(quA[0][ks], kf, ac[0][g]);
                ac[1][g] = mfma16(quA[1][ks], kf, ac[1][g]);
            }

        // ---- BD bands: union window = logical groups base6..base6+5 ----
        floatx4 bd[2][5];
#pragma unroll
        for (int g = 0; g < 5; ++g) { bd[0][g] = z4; bd[1][g] = z4; }
        const int base6 = 4 * ib + 6 - 2 * w;
#pragma unroll
        for (int gbu = 0; gbu < 6; ++gbu) {
            const int sl = (base6 + gbu) & 15;
#pragma unroll
            for (int ks = 0; ks < 4; ++ks) {
                const short8 pf = *(const short8*)&P_lds[sl][(ks * 64 + lane) * 8];
                if (gbu < 5)  bd[1][gbu]     = mfma16(qvA[1][ks], pf, bd[1][gbu]);
                if (gbu >= 1) bd[0][gbu - 1] = mfma16(qvA[0][ks], pf, bd[0][gbu - 1]);
            }
        }

        // ---- softmax per sub-block ----
#pragma unroll
        for (int mt = 0; mt < 2; ++mt) {
            float pr[4][4];
            float mc[4], alpha[4];
#pragma unroll
            for (int i = 0; i < 4; ++i) {
                float mm = -1e30f;
#pragma unroll
                for (int g = 0; g < 4; ++g) {
                    const float lo = __shfl(bd[mt][g][i],     src[i], 64);
                    const float hh = __shfl(bd[mt][g + 1][i], src[i], 64);
                    const float s  = (ac[mt][g][i] + (hi[i] ? hh : lo)) * scale;
                    pr[g][i] = s;
                    mm = fmaxf(mm, s);
                }
                mc[i] = mm;
            }
#pragma unroll
            for (int i = 0; i < 4; ++i) {
#pragma unroll
                for (int mk = 1; mk < 16; mk <<= 1)
                    mc[i] = fmaxf(mc[i], __shfl_xor(mc[i], mk));
                const float mn = fmaxf(mrun[mt][i], mc[i]);
                alpha[i] = __expf(mrun[mt][i] - mn);
                mrun[mt][i] = mn;
                float ls = 0.f;
#pragma unroll
                for (int g = 0; g < 4; ++g) {
                    const float e = __expf(pr[g][i] - mn);
                    pr[g][i] = e;
                    ls += e;
                }
#pragma unroll
                for (int mk = 1; mk < 16; mk <<= 1)
                    ls += __shfl_xor(ls, mk);
                lrun[mt][i] = lrun[mt][i] * alpha[i] + ls;
            }
#pragma unroll
            for (int g = 0; g < 8; ++g)
#pragma unroll
                for (int i = 0; i < 4; ++i) o[mt][g][i] *= alpha[i];
            // probs C->A via per-wave fragment-ordered LDS
#pragma unroll
            for (int g = 0; g < 4; ++g) {
                const int unit = (g >> 1) * 4 + (g & 1) * 2 + (r15 >> 3);
#pragma unroll
                for (int i = 0; i < 4; ++i)
                    pr_lds[w][mt][(unit * 16 + quad * 4 + i) * 8 + (r15 & 7)] = f2bf(pr[g][i]);
            }
        }

        // ---- PV: each V-frag feeds both mt ----
        short8 pa[2][2];
#pragma unroll
        for (int mt = 0; mt < 2; ++mt)
#pragma unroll
            for (int ks2 = 0; ks2 < 2; ++ks2)
                pa[mt][ks2] = *(const short8*)&pr_lds[w][mt][(ks2 * 64 + lane) * 8];
#pragma unroll
        for (int og = 0; og < 8; ++og)
#pragma unroll
            for (int ks2 = 0; ks2 < 2; ++ks2) {
                const short8 vf = *(const short8*)&V_lds[cur][((og * 2 + ks2) * 64 + lane) * 8];
                o[0][og] = mfma16(pa[0][ks2], vf, o[0][og]);
                o[1][og] = mfma16(pa[1][ks2], vf, o[1][og]);
            }
        __syncthreads();
    }

    // ---- epilogue ----
#pragma unroll
    for (int mt = 0; mt < 2; ++mt) {
        float inv[4];
#pragma unroll
        for (int i = 0; i < 4; ++i) inv[i] = 1.0f / lrun[mt][i];
#pragma unroll
        for (int og = 0; og < 8; ++og)
#pragma unroll
            for (int i = 0; i < 4; ++i) {
                const size_t idx =
                    ((size_t)(b * T_ + q0b + w * 32 + mt * 16 + quad * 4 + i)) * D_
                    + h * DK_ + og * 16 + r15;
                ao[idx] = f2bf(o[mt][og][i] * inv[i]);
            }
    }
}

// ---------------------------------------------------------------------------
extern "C" void kernel_launch(void* const* d_in, const int* in_sizes, int n_in,
                              void* d_out, int out_size, void* d_ws, size_t ws_size,
                              hipStream_t stream) {
    const void* x  = d_in[0];
    const void* pe = d_in[1];
    const void* Wq = d_in[2];
    const void* Wk = d_in[3];
    const void* Wv = d_in[4];
    const void* Wo = d_in[5];
    const void* Wp = d_in[6];
    const void* ub = d_in[7];
    const void* vb = d_in[8];

    int* flag = (int*)d_ws;
    ushort_t* arena = (ushort_t*)d_ws + 16;   // +32 B
    ushort_t* xb   = arena;                    // 8,388,608   (reused as ao_ws)
    ushort_t* peb  = arena + 8388608;          // 4096 rows (last = junk)
    ushort_t* wqb  = arena + 12582912;         // Wq|Wk|Wv contiguous
    ushort_t* wob  = wqb + 3 * 1048576;
    ushort_t* wpb  = wob + 1048576;
    ushort_t* ubb  = arena + 17825792;
    ushort_t* vbb  = ubb + 1024;
    ushort_t* q_ws  = arena + 17827840;        // q | k | v^T contiguous
    ushort_t* p_ws  = q_ws + 3 * 8388608;      // [H,PS_,DK]
    ushort_t* ao_ws = xb;                      // x dead after QKV GEMM

    detect_kernel<<<1, 64, 0, stream>>>((const ushort_t*)x, flag);

    const int cvb = CV_TOT / 4 / 256;
    convert_kernel<0><<<cvb, 256, 0, stream>>>(flag, x, pe, Wq, Wk, Wv, Wo, Wp, ub, vb, arena);
    convert_kernel<1><<<cvb, 256, 0, stream>>>(flag, x, pe, Wq, Wk, Wv, Wo, Wp, ub, vb, arena);

    gemm_mfma<<<dim3(24, 64), 256, 0, stream>>>(flag, xb,  wqb, q_ws, 5);  // fused QKV
    gemm_mfma<<<dim3(8, 32),  256, 0, stream>>>(flag, peb, wpb, p_ws, 1);  // P

    attn_mfma<<<dim3(T_ / 128, B_ * H_), 256, 0, stream>>>(
        q_ws, q_ws + 8388608, q_ws + 16777216, p_ws, ubb, vbb, ao_ws);

    gemm_mfma<<<dim3(8, 64), 256, 0, stream>>>(flag, ao_ws, wob, d_out, 3);
    gemm_mfma<<<dim3(8, 64), 256, 0, stream>>>(flag, ao_ws, wob, d_out, 4);
}